// Round 9
// baseline (47.163 us; speedup 1.0000x reference)
//
#include <hip/hip_runtime.h>
#include <hip/hip_bf16.h>
#include <math.h>

// QConv2d: new_rho = kron(Ux,Uy) @ rho @ kron(Ux,Uy)^T
// Ux,Uy 32x32 block-diagonal with four IDENTICAL 8x8 orthogonal blocks.
// Four independent length-8 contractions on axes (x1,y1,x2,y2).
//
// r9: x1-half BLOCK SPLIT for occupancy. Block = (b,bx1,by1,bx2,x1h):
// 2048 blocks x 256 threads (8 blocks/CU vs 4 before).
//  - thread t owns column bx2*256+t: loads ALL 64 rows (redundant 2x across
//    the x1h pair; L2/L3 absorbs), streams k: y1-transform (64 FMA) +
//    x1-half accumulate into acc[32] (32 FMA) -> 768 FMA total.
//  - stage 32 transformed rows as bf16, swizzled: 16 KB LDS (10 blocks/CU).
//  - ONE barrier.
//  - consume: (rr=t&31, by2=(t>>5)&3, x2h=t>>7): 8x ds_read_b128,
//    y2-transform (redundant over x2h) + x2-half mix -> 768 FMA, q[32].
//  - direct float4 stores.
// Per-thread regs ~55-64 -> up to 8 waves/SIMD; target ~28-32 waves/CU.

__global__ void setup_uf(const float* __restrict__ phi_x,
                         const float* __restrict__ phi_y,
                         float* __restrict__ ws) {
    const int t = threadIdx.x;
    if (t < 2) {
        const float* phi = (t == 0) ? phi_x : phi_y;
        float U[8][8];
#pragma unroll
        for (int i = 0; i < 8; ++i)
#pragma unroll
            for (int j = 0; j < 8; ++j) U[i][j] = (i == j) ? 1.0f : 0.0f;
        int idx = 0;
#pragma unroll
        for (int i = 1; i < 8; ++i) {
#pragma unroll
            for (int j = i; j >= 1; --j) {
                const float c = cosf(phi[idx]);
                const float s = sinf(phi[idx]);
#pragma unroll
                for (int m = 0; m < 8; ++m) {
                    const float a = U[j - 1][m], b = U[j][m];
                    U[j - 1][m] = c * a + s * b;
                    U[j][m]     = -s * a + c * b;
                }
                ++idx;
            }
        }
        float* o = ws + t * 64;
#pragma unroll
        for (int i = 0; i < 8; ++i)
#pragma unroll
            for (int j = 0; j < 8; ++j) o[i * 8 + j] = U[i][j];
    }
}

__global__ __launch_bounds__(256) void qconv_fused(const float* __restrict__ rho,
                                                   const float* __restrict__ ws,
                                                   float* __restrict__ out) {
    // [32 rows][32 slots of 8 bf16], slot-swizzled: 16 KB
    __shared__ __align__(16) unsigned short Sh[8192];
    const int t   = threadIdx.x;
    const int bid = blockIdx.x;
    const int bx2 = bid & 3;
    const int by1 = (bid >> 2) & 3;
    const int bx1 = (bid >> 4) & 3;
    const int x1h = (bid >> 6) & 1;
    const int b   = bid >> 7;

    const float* __restrict__ UX = ws;       // Ufx[8][8] (uniform -> s_load)
    const float* __restrict__ UY = ws + 64;  // Ufy[8][8]

    const size_t B0      = (size_t)b << 20;
    const int    rowbase = bx1 * 256 + by1 * 8;
    const int    cg      = bx2 * 256 + t;

    const float* __restrict__ src = rho + B0 + (size_t)rowbase * 1024 + cg;

    // ---- pass 1: stream k-groups; y1-transform + x1-HALF accumulate ----
    float acc[32];
#pragma unroll
    for (int k = 0; k < 8; ++k) {
        float raw[8];
#pragma unroll
        for (int j = 0; j < 8; ++j)
            raw[j] = src[(size_t)(k * 32 + j) * 1024];
        float w[8];
#pragma unroll
        for (int jj = 0; jj < 8; ++jj) {
            float a = 0.0f;
#pragma unroll
            for (int j = 0; j < 8; ++j)
                a = fmaf(UY[jj * 8 + j], raw[j], a);
            w[jj] = a;
        }
#pragma unroll
        for (int ii = 0; ii < 4; ++ii) {
            const float ux = UX[(x1h * 4 + ii) * 8 + k];
#pragma unroll
            for (int jj = 0; jj < 8; ++jj) {
                if (k == 0) acc[ii * 8 + jj] = ux * w[jj];
                else        acc[ii * 8 + jj] = fmaf(ux, w[jj], acc[ii * 8 + jj]);
            }
        }
    }

    // ---- stage 32 rows as bf16, swizzled (conflict-free b16 writes) ----
    {
        const int sb = t >> 3;  // natural 16B slot
        const int il = t & 7;   // element within slot
#pragma unroll
        for (int r = 0; r < 32; ++r) {
            const int slot = sb ^ ((r << 1) & 31);
            __hip_bfloat16 h = __float2bfloat16(acc[r]);
            Sh[r * 256 + slot * 8 + il] = *reinterpret_cast<unsigned short*>(&h);
        }
    }
    __syncthreads();

    // ---- consume: (rr, by2, x2h); y2-transform + x2-half mix ----
    const int rr  = t & 31;
    const int by2 = (t >> 5) & 3;
    const int x2h = t >> 7;
    const int rsw = (rr << 1) & 31;
    const unsigned short* __restrict__ Srow = Sh + rr * 256;

    float q[32];
#pragma unroll
    for (int x2 = 0; x2 < 8; ++x2) {
        const int slot = (x2 * 4 + by2) ^ rsw;
        const uint4 u = *reinterpret_cast<const uint4*>(Srow + slot * 8);
        float raw[8];
        raw[0] = __uint_as_float(u.x << 16);
        raw[1] = __uint_as_float(u.x & 0xffff0000u);
        raw[2] = __uint_as_float(u.y << 16);
        raw[3] = __uint_as_float(u.y & 0xffff0000u);
        raw[4] = __uint_as_float(u.z << 16);
        raw[5] = __uint_as_float(u.z & 0xffff0000u);
        raw[6] = __uint_as_float(u.w << 16);
        raw[7] = __uint_as_float(u.w & 0xffff0000u);

        float w8[8];
#pragma unroll
        for (int jj = 0; jj < 8; ++jj) {
            float a = 0.0f;
#pragma unroll
            for (int j = 0; j < 8; ++j)
                a = fmaf(UY[jj * 8 + j], raw[j], a);
            w8[jj] = a;
        }
#pragma unroll
        for (int xp = 0; xp < 4; ++xp) {
            const float ux = UX[(x2h * 4 + xp) * 8 + x2];
#pragma unroll
            for (int jj = 0; jj < 8; ++jj) {
                if (x2 == 0) q[xp * 8 + jj] = ux * w8[jj];
                else         q[xp * 8 + jj] = fmaf(ux, w8[jj], q[xp * 8 + jj]);
            }
        }
    }

    // ---- stores: row gr, cols bx2*256 + x2h*128 + xp*32 + by2*8 ----
    const int gr = rowbase + (x1h * 4 + (rr >> 3)) * 32 + (rr & 7);
    float* __restrict__ dst =
        out + B0 + (size_t)gr * 1024 + bx2 * 256 + x2h * 128 + by2 * 8;
#pragma unroll
    for (int xp = 0; xp < 4; ++xp) {
        *reinterpret_cast<float4*>(dst + xp * 32) =
            make_float4(q[xp * 8 + 0], q[xp * 8 + 1], q[xp * 8 + 2], q[xp * 8 + 3]);
        *reinterpret_cast<float4*>(dst + xp * 32 + 4) =
            make_float4(q[xp * 8 + 4], q[xp * 8 + 5], q[xp * 8 + 6], q[xp * 8 + 7]);
    }
}

extern "C" void kernel_launch(void* const* d_in, const int* in_sizes, int n_in,
                              void* d_out, int out_size, void* d_ws, size_t ws_size,
                              hipStream_t stream) {
    const float* rho   = (const float*)d_in[0];
    const float* phi_x = (const float*)d_in[1];
    const float* phi_y = (const float*)d_in[2];
    float* out = (float*)d_out;
    float* ws  = (float*)d_ws;

    setup_uf<<<1, 64, 0, stream>>>(phi_x, phi_y, ws);
    qconv_fused<<<2048, 256, 0, stream>>>(rho, ws, out);
}

// Round 10
// 44.789 us; speedup vs baseline: 1.0530x; 1.0530x over previous
//
#include <hip/hip_runtime.h>
#include <hip/hip_bf16.h>
#include <math.h>

// QConv2d: new_rho = kron(Ux,Uy) @ rho @ kron(Ux,Uy)^T
// M(1024x1024) is block-diagonal: 16 copies of W = Ufx(8x8) (x) Ufy(8x8),
// a dense 64x64 orthogonal operator. So per 64x64 (block-row, block-col)
// tile T:  O = W @ T @ W^T  -> two 64x64x64 GEMMs -> MFMA.
//
// r10 (MFMA rewrite): one WAVE per tile, 4096 waves = 1024 blocks x 256.
// No barriers (waves independent). Per wave:
//  - stage T^T to LDS as bf16 [64 cols][64 k], chunk-XOR swizzled (8KB),
//  - m-loop x4: GEMM1 P(16x64) = W[m-rows] @ T  (8x mfma_16x16x32_bf16,
//    A-frags = W from global (L1-hot), B-frags = T^T from LDS),
//    round P->bf16 into 2KB LDS strip (wave-private, no barrier),
//    GEMM2 O(16x64) = P @ W^T (8 MFMA, B-frags = W rows re-read),
//    direct dword stores (4 waves/block interleave by2 -> full 128B lines).
// LDS: 4 waves x (8KB T + 2KB P) = 40960B -> exactly 4 blocks/CU (160KB).
// Precision: two bf16 roundings (input, P); r8 measured 0.031 with one;
// threshold 0.107.

typedef __attribute__((ext_vector_type(8))) short short8_t;  // 8 bf16
typedef __attribute__((ext_vector_type(4))) float f32x4;

__global__ void setup_w(const float* __restrict__ phi_x,
                        const float* __restrict__ phi_y,
                        unsigned short* __restrict__ W) {
    __shared__ float U[2][64];
    const int t = threadIdx.x;
    if (t < 2) {
        const float* phi = (t == 0) ? phi_x : phi_y;
        float Um[8][8];
#pragma unroll
        for (int i = 0; i < 8; ++i)
#pragma unroll
            for (int j = 0; j < 8; ++j) Um[i][j] = (i == j) ? 1.0f : 0.0f;
        int idx = 0;
#pragma unroll
        for (int i = 1; i < 8; ++i) {
#pragma unroll
            for (int j = i; j >= 1; --j) {
                const float c = cosf(phi[idx]);
                const float s = sinf(phi[idx]);
#pragma unroll
                for (int m = 0; m < 8; ++m) {
                    const float a = Um[j - 1][m], b = Um[j][m];
                    Um[j - 1][m] = c * a + s * b;
                    Um[j][m]     = -s * a + c * b;
                }
                ++idx;
            }
        }
#pragma unroll
        for (int i = 0; i < 8; ++i)
#pragma unroll
            for (int j = 0; j < 8; ++j) U[t][i * 8 + j] = Um[i][j];
    }
    __syncthreads();
    // thread t = row i of W: i = xi*8+yi; W[i][j] = Ufx[xi][xj]*Ufy[yi][yj]
    const int xi = t >> 3, yi = t & 7;
#pragma unroll
    for (int j = 0; j < 64; ++j) {
        const int xj = j >> 3, yj = j & 7;
        const float w = U[0][xi * 8 + xj] * U[1][yi * 8 + yj];
        __hip_bfloat16 h = __float2bfloat16(w);
        W[t * 64 + j] = *reinterpret_cast<const unsigned short*>(&h);
    }
}

__device__ __forceinline__ unsigned short bf16bits(float v) {
    __hip_bfloat16 h = __float2bfloat16(v);
    return *reinterpret_cast<const unsigned short*>(&h);
}

__global__ __launch_bounds__(256) void qconv_mfma(const float* __restrict__ rho,
                                                  const unsigned short* __restrict__ Wg,
                                                  float* __restrict__ out) {
    // per-wave: Tt[64][64] bf16 (chunk-swizzled) + P[16][64] bf16
    __shared__ __align__(16) unsigned short lds[20480];  // 40960 B
    const int t   = threadIdx.x;
    const int wid = t >> 6;
    const int l   = t & 63;

    const int g  = blockIdx.x * 4 + wid;   // tile id
    const int bj = g & 15;                 // col block (bx2*4+by2)
    const int bi = (g >> 4) & 15;          // row block (bx1*4+by1)
    const int b  = g >> 8;                 // batch

    const int rowb = (bi >> 2) * 256 + (bi & 3) * 8;
    const int colb = (bj >> 2) * 256 + (bj & 3) * 8;
    const size_t B0 = (size_t)b << 20;

    unsigned short* __restrict__ Tt = lds + wid * 5120;
    unsigned short* __restrict__ Pb = Tt + 4096;

    // ---- stage T^T: lane l = tile col; loop s = tile row (k index) ----
    // swizzle: k-chunk kc stored at chunk (kc ^ (col&7)) within the row.
    {
        const float* __restrict__ src =
            rho + B0 + (size_t)rowb * 1024 + colb + ((l >> 3) * 32 + (l & 7));
        const int l7 = l & 7;
#pragma unroll
        for (int s = 0; s < 64; ++s) {
            const float v = src[(size_t)((s >> 3) * 32 + (s & 7)) * 1024];
            Tt[l * 64 + ((((s >> 3) ^ l7) << 3) | (s & 7))] = bf16bits(v);
        }
    }

    const int ln = l & 15;       // fragment row/col lane index
    const int q  = l >> 4;       // k-quarter
    const int l7 = ln & 7;

    // W fragment byte offsets (global, row-major [64][64] bf16):
    // frag(row0, k0): lane reads W[(row0+ln)*64 + k0 + q*8], 8 bf16 = 16B.
#pragma unroll 1
    for (int m = 0; m < 4; ++m) {
        // ---- GEMM1: P[m-chunk] = W[m-rows] @ T ----
        const short8_t a0 =
            *reinterpret_cast<const short8_t*>(Wg + ((m * 16 + ln) << 6) + (q << 3));
        const short8_t a1 =
            *reinterpret_cast<const short8_t*>(Wg + ((m * 16 + ln) << 6) + 32 + (q << 3));
        f32x4 pacc[4];
#pragma unroll
        for (int n = 0; n < 4; ++n) {
            // B-frag: T[k][col = n*16+ln], k = k0 + q*8; from T^T swizzled
            const short8_t b0 = *reinterpret_cast<const short8_t*>(
                Tt + (n * 16 + ln) * 64 + ((q ^ l7) << 3));
            const short8_t b1 = *reinterpret_cast<const short8_t*>(
                Tt + (n * 16 + ln) * 64 + (((4 + q) ^ l7) << 3));
            f32x4 c = {0.0f, 0.0f, 0.0f, 0.0f};
            c = __builtin_amdgcn_mfma_f32_16x16x32_bf16(a0, b0, c, 0, 0, 0);
            c = __builtin_amdgcn_mfma_f32_16x16x32_bf16(a1, b1, c, 0, 0, 0);
            pacc[n] = c;
        }

        // ---- round P to bf16 in LDS (wave-private, same swizzle) ----
#pragma unroll
        for (int n = 0; n < 4; ++n)
#pragma unroll
            for (int i = 0; i < 4; ++i) {
                const int rl = q * 4 + i;           // P row 0..15
                const int c  = n * 16 + ln;         // P col 0..63
                Pb[rl * 64 + ((((c >> 3) ^ (rl & 7)) << 3) | (c & 7))] =
                    bf16bits(pacc[n][i]);
            }

        // ---- GEMM2: O[m-chunk] = P @ W^T ----
        // A-frag: P[row=ln][k = k0 + q*8]
        const short8_t pa0 = *reinterpret_cast<const short8_t*>(
            Pb + ln * 64 + ((q ^ l7) << 3));
        const short8_t pa1 = *reinterpret_cast<const short8_t*>(
            Pb + ln * 64 + (((4 + q) ^ l7) << 3));
#pragma unroll
        for (int n = 0; n < 4; ++n) {
            // B-frag: W^T[k][col = n*16+ln] = W[n*16+ln][k]
            const short8_t wb0 = *reinterpret_cast<const short8_t*>(
                Wg + ((n * 16 + ln) << 6) + (q << 3));
            const short8_t wb1 = *reinterpret_cast<const short8_t*>(
                Wg + ((n * 16 + ln) << 6) + 32 + (q << 3));
            f32x4 c = {0.0f, 0.0f, 0.0f, 0.0f};
            c = __builtin_amdgcn_mfma_f32_16x16x32_bf16(pa0, wb0, c, 0, 0, 0);
            c = __builtin_amdgcn_mfma_f32_16x16x32_bf16(pa1, wb1, c, 0, 0, 0);

            // store: lane holds O[R][C], R = m*16 + q*4 + i, C = n*16 + ln
#pragma unroll
            for (int i = 0; i < 4; ++i) {
                const int rr   = q * 4 + i;
                const int grow = rowb + (m * 2 + (rr >> 3)) * 32 + (rr & 7);
                const int gcol = colb + (n * 2 + (ln >> 3)) * 32 + (ln & 7);
                out[B0 + (size_t)grow * 1024 + gcol] = c[i];
            }
        }
    }
}

extern "C" void kernel_launch(void* const* d_in, const int* in_sizes, int n_in,
                              void* d_out, int out_size, void* d_ws, size_t ws_size,
                              hipStream_t stream) {
    const float* rho   = (const float*)d_in[0];
    const float* phi_x = (const float*)d_in[1];
    const float* phi_y = (const float*)d_in[2];
    float* out = (float*)d_out;
    unsigned short* W = (unsigned short*)d_ws;

    setup_w<<<1, 64, 0, stream>>>(phi_x, phi_y, W);
    qconv_mfma<<<1024, 256, 0, stream>>>(rho, W, out);
}

// Round 11
// 43.796 us; speedup vs baseline: 1.0769x; 1.0227x over previous
//
#include <hip/hip_runtime.h>
#include <hip/hip_bf16.h>
#include <math.h>

// QConv2d: new_rho = kron(Ux,Uy) @ rho @ kron(Ux,Uy)^T
// Per 64x64 tile T (block-row set x block-col set): O = W T W^T with
// W = Ufx (x) Ufy (64x64, shared). Computed as O^T = (W T^T) W^T so that
// ALL MFMA B/A fragments read CONTIGUOUS 16B from row-major LDS/global.
//
// r11: fully row-contiguous global IO (the 41us wall r2-r10 shared was
// column-walk / scattered global access; fill kernel hits 6.6TB/s with
// contiguous lines).
//  - block = (b, bi, col-half): 64 block-rows x 512 cols, 512 thr, grid 512.
//  - stage-in: float4 loads, EVERY instr 1KB contiguous; bf16 -> LDS
//    pair-tiles [64][128] chunk-XOR^(row&15) (b64 writes ~conflict-free).
//  - per wave: tile GEMM1 Q16 = W[m] @ T^T (B = contiguous b128 from
//    row-major T), Q16 via 2KB LDS strip, GEMM2 O16^T = Q16 @ W^T.
//  - stores: i-packed float4 -> every store instr = 16 full 64B sectors.
// LDS 80KB dynamic -> 2 blocks/CU (16 waves). 2 bf16 roundings (r10: 0.031).

typedef __attribute__((ext_vector_type(8))) short short8_t;  // 8 bf16
typedef __attribute__((ext_vector_type(4))) float f32x4;

__global__ void setup_w(const float* __restrict__ phi_x,
                        const float* __restrict__ phi_y,
                        unsigned short* __restrict__ W) {
    __shared__ float U[2][64];
    const int t = threadIdx.x;
    if (t < 2) {
        const float* phi = (t == 0) ? phi_x : phi_y;
        float Um[8][8];
#pragma unroll
        for (int i = 0; i < 8; ++i)
#pragma unroll
            for (int j = 0; j < 8; ++j) Um[i][j] = (i == j) ? 1.0f : 0.0f;
        int idx = 0;
#pragma unroll
        for (int i = 1; i < 8; ++i) {
#pragma unroll
            for (int j = i; j >= 1; --j) {
                const float c = cosf(phi[idx]);
                const float s = sinf(phi[idx]);
#pragma unroll
                for (int m = 0; m < 8; ++m) {
                    const float a = Um[j - 1][m], b = Um[j][m];
                    Um[j - 1][m] = c * a + s * b;
                    Um[j][m]     = -s * a + c * b;
                }
                ++idx;
            }
        }
#pragma unroll
        for (int i = 0; i < 8; ++i)
#pragma unroll
            for (int j = 0; j < 8; ++j) U[t][i * 8 + j] = Um[i][j];
    }
    __syncthreads();
    const int xi = t >> 3, yi = t & 7;
#pragma unroll
    for (int j = 0; j < 64; ++j) {
        const int xj = j >> 3, yj = j & 7;
        const float w = U[0][xi * 8 + xj] * U[1][yi * 8 + yj];
        __hip_bfloat16 h = __float2bfloat16(w);
        W[t * 64 + j] = *reinterpret_cast<const unsigned short*>(&h);
    }
}

__device__ __forceinline__ unsigned short bf16bits(float v) {
    __hip_bfloat16 h = __float2bfloat16(v);
    return *reinterpret_cast<const unsigned short*>(&h);
}

__global__ __launch_bounds__(512) void qconv_mfma2(const float* __restrict__ rho,
                                                   const unsigned short* __restrict__ Wg,
                                                   float* __restrict__ out) {
    extern __shared__ __align__(16) unsigned short L[];  // 40960 shorts = 80KB
    // layout: 4 pair-tiles x 8192 shorts ([64 rows][128 cols] swizzled),
    //         then 8 Q-strips x 1024 shorts ([16][64] swizzled).
    const int t  = threadIdx.x;
    const int w  = t >> 6;   // wave 0..7 = tile id within block
    const int l  = t & 63;

    const int bid = blockIdx.x;
    const int ch  = bid & 1;
    const int bi  = (bid >> 1) & 15;
    const int b   = bid >> 5;

    const int    rowb    = (bi >> 2) * 256 + (bi & 3) * 8;
    const size_t B0      = (size_t)b << 20;
    const int    colbase = ch * 512;

    // ================= stage-in: all-contiguous 1KB loads =================
    {
        float4 v[16];
#pragma unroll
        for (int j = 0; j < 8; ++j) {
            const float* __restrict__ src =
                rho + B0 + (size_t)(rowb + w * 32 + j) * 1024 + colbase;
#pragma unroll
            for (int k2 = 0; k2 < 2; ++k2)
                v[j * 2 + k2] =
                    *reinterpret_cast<const float4*>(src + 4 * l + 256 * k2);
        }
#pragma unroll
        for (int j = 0; j < 8; ++j) {
            const int rt = 8 * w + j;  // T-row index (same for all tiles)
#pragma unroll
            for (int k2 = 0; k2 < 2; ++k2) {
                const int gc = 4 * l + 256 * k2;  // col within 512
                const int u     = ((gc >> 8) << 1) | ((gc >> 4) & 1);
                const int pcolc = ((gc >> 3) & 1) * 8 + ((gc >> 5) & 7);
                const int chunk = pcolc ^ (rt & 15);
                ushort4 h;
                const float4 x = v[j * 2 + k2];
                h.x = bf16bits(x.x); h.y = bf16bits(x.y);
                h.z = bf16bits(x.z); h.w = bf16bits(x.w);
                *reinterpret_cast<ushort4*>(
                    &L[u * 8192 + rt * 128 + (chunk << 3) + (gc & 7)]) = h;
            }
        }
    }
    __syncthreads();

    // ================= per-wave tile GEMMs =================
    const int ln = l & 15;   // fragment row/col lane index
    const int q  = l >> 4;   // k-group
    const unsigned short* __restrict__ Tp = &L[(w >> 1) * 8192];
    unsigned short* __restrict__ Qs       = &L[32768 + w * 1024];
    const int wc = (w & 1) * 8;  // chunk offset of this tile within pair

    const int bx2 = 2 * ch + (w >> 2);
    const int by2 = w & 3;

#pragma unroll 1
    for (int m = 0; m < 4; ++m) {
        // ---- GEMM1: Q16 = W[16m..16m+16) @ T^T ----
        const short8_t AW0 = *reinterpret_cast<const short8_t*>(
            Wg + (16 * m + ln) * 64 + q * 8);
        const short8_t AW1 = *reinterpret_cast<const short8_t*>(
            Wg + (16 * m + ln) * 64 + 32 + q * 8);
        f32x4 acc[4];
#pragma unroll
        for (int tc = 0; tc < 4; ++tc) {
            const int prow = 16 * tc + ln;  // T row (= T^T col n)
            const short8_t BT0 = *reinterpret_cast<const short8_t*>(
                Tp + prow * 128 + (((wc + 0 + q) ^ (prow & 15)) << 3));
            const short8_t BT1 = *reinterpret_cast<const short8_t*>(
                Tp + prow * 128 + (((wc + 4 + q) ^ (prow & 15)) << 3));
            f32x4 c = {0.0f, 0.0f, 0.0f, 0.0f};
            c = __builtin_amdgcn_mfma_f32_16x16x32_bf16(AW0, BT0, c, 0, 0, 0);
            c = __builtin_amdgcn_mfma_f32_16x16x32_bf16(AW1, BT1, c, 0, 0, 0);
            acc[tc] = c;
        }

        // ---- Q16 -> LDS strip (bf16, row-major [16][64], chunk-XOR row&7) ----
#pragma unroll
        for (int tc = 0; tc < 4; ++tc)
#pragma unroll
            for (int i = 0; i < 4; ++i) {
                const int qrow = 4 * q + i;
                const int qcol = 16 * tc + ln;
                Qs[qrow * 64 + (((qcol >> 3) ^ (qrow & 7)) << 3) + (qcol & 7)] =
                    bf16bits(acc[tc][i]);
            }

        // ---- GEMM2: O16^T = Q16 @ W^T ; direct full-sector stores ----
        const short8_t AQ0 = *reinterpret_cast<const short8_t*>(
            Qs + ln * 64 + (((0 + q) ^ (ln & 7)) << 3));
        const short8_t AQ1 = *reinterpret_cast<const short8_t*>(
            Qs + ln * 64 + (((4 + q) ^ (ln & 7)) << 3));
#pragma unroll
        for (int tc = 0; tc < 4; ++tc) {
            const short8_t BW0 = *reinterpret_cast<const short8_t*>(
                Wg + (16 * tc + ln) * 64 + q * 8);
            const short8_t BW1 = *reinterpret_cast<const short8_t*>(
                Wg + (16 * tc + ln) * 64 + 32 + q * 8);
            f32x4 o = {0.0f, 0.0f, 0.0f, 0.0f};
            o = __builtin_amdgcn_mfma_f32_16x16x32_bf16(AQ0, BW0, o, 0, 0, 0);
            o = __builtin_amdgcn_mfma_f32_16x16x32_bf16(AQ1, BW1, o, 0, 0, 0);

            // lane holds O[16tc+ln][16m+4q+i], i=0..3 -> one float4
            const int grow = rowb + (2 * tc + (ln >> 3)) * 32 + (ln & 7);
            const int c0   = 16 * m + 4 * q;
            const int gcol = bx2 * 256 + (c0 >> 3) * 32 + by2 * 8 + (c0 & 7);
            *reinterpret_cast<float4*>(out + B0 + (size_t)grow * 1024 + gcol) =
                make_float4(o[0], o[1], o[2], o[3]);
        }
    }
}

extern "C" void kernel_launch(void* const* d_in, const int* in_sizes, int n_in,
                              void* d_out, int out_size, void* d_ws, size_t ws_size,
                              hipStream_t stream) {
    const float* rho   = (const float*)d_in[0];
    const float* phi_x = (const float*)d_in[1];
    const float* phi_y = (const float*)d_in[2];
    float* out = (float*)d_out;
    unsigned short* W = (unsigned short*)d_ws;

    setup_w<<<1, 64, 0, stream>>>(phi_x, phi_y, W);
    qconv_mfma2<<<512, 512, 81920, stream>>>(rho, W, out);
}